// Round 1
// baseline (541.584 us; speedup 1.0000x reference)
//
#include <hip/hip_runtime.h>
#include <math.h>

#define B 4
#define C 64
#define L 4096
#define OUTC 64
#define SCALE 10.0f
#define THRESH 1e-3f

// ---------------------------------------------------------------------------
// Prep: transpose W2 [64,128] -> W2t [128,64] so projection reads it
// contiguously (wave-uniform consecutive addresses -> s_load_dwordx vectors).
// ---------------------------------------------------------------------------
__global__ void w2_transpose_kernel(const float* __restrict__ W2,
                                    float* __restrict__ W2t) {
    int i = blockIdx.x * 256 + threadIdx.x;  // 0 .. 8191
    if (i < OUTC * 2 * C) {
        int j = i >> 7;    // 0..63   row of W2
        int o = i & 127;   // 0..127  col of W2
        W2t[o * OUTC + j] = W2[j * (2 * C) + o];
    }
}

// ---------------------------------------------------------------------------
// Projection: p = l2norm(W2 @ leaky(W1 @ x)) per column.
// One thread per (input, b, l) column. 64 threads/block, 512 blocks.
// x column (64) and y accumulators (64) live in VGPRs; W1/W2t accesses are
// wave-uniform (scalar-load path).
// ---------------------------------------------------------------------------
__global__ void __launch_bounds__(64) proj_kernel(
    const float* __restrict__ q_in, const float* __restrict__ k_in,
    const float* __restrict__ W1, const float* __restrict__ W2t,
    float* __restrict__ qp, float* __restrict__ kp)
{
    int bid   = blockIdx.x;        // 0..511
    int which = bid >> 8;          // 0 = query, 1 = key
    int blk   = bid & 255;
    int col   = blk * 64 + threadIdx.x;   // 0..16383
    int b     = col >> 12;                // /4096
    int l     = col & (L - 1);

    const float* __restrict__ src = which ? k_in : q_in;
    float* __restrict__ dst       = which ? kp : qp;

    float xr[C];
    #pragma unroll
    for (int c = 0; c < C; ++c)
        xr[c] = src[((size_t)b * C + c) * L + l];

    float y[OUTC];
    #pragma unroll
    for (int j = 0; j < OUTC; ++j) y[j] = 0.0f;

    #pragma unroll 2
    for (int o = 0; o < 2 * C; ++o) {
        float h0 = 0.f, h1 = 0.f, h2 = 0.f, h3 = 0.f;
        #pragma unroll
        for (int c = 0; c < C; c += 4) {
            h0 = fmaf(W1[o * C + c + 0], xr[c + 0], h0);
            h1 = fmaf(W1[o * C + c + 1], xr[c + 1], h1);
            h2 = fmaf(W1[o * C + c + 2], xr[c + 2], h2);
            h3 = fmaf(W1[o * C + c + 3], xr[c + 3], h3);
        }
        float h = (h0 + h1) + (h2 + h3);
        h = (h >= 0.0f) ? h : 0.01f * h;          // LeakyReLU(0.01)
        #pragma unroll
        for (int j = 0; j < OUTC; ++j)
            y[j] = fmaf(W2t[o * OUTC + j], h, y[j]);
    }

    // F.normalize over channel dim, eps = 1e-12
    float s = 0.f;
    #pragma unroll
    for (int j = 0; j < OUTC; ++j) s = fmaf(y[j], y[j], s);
    float inv = 1.0f / fmaxf(sqrtf(s), 1e-12f);

    #pragma unroll
    for (int j = 0; j < OUTC; ++j)
        dst[((size_t)b * OUTC + j) * L + l] = y[j] * inv;
}

// ---------------------------------------------------------------------------
// Scores + softmax + threshold. One block per (b, 8-row tile).
// Each thread: all 8 rows x 16 m-columns (8 float2 pairs), S[8][16] in regs.
// k read as float2 (coalesced); q tile broadcast from LDS.
// ---------------------------------------------------------------------------
__global__ void __launch_bounds__(256, 2) scores_kernel(
    const float* __restrict__ qp, const float* __restrict__ kp,
    float* __restrict__ out)
{
    int bid = blockIdx.x;            // 0..2047
    int b   = bid >> 9;              // /512
    int l0  = (bid & 511) << 3;      // *8
    int t   = threadIdx.x;           // 0..255

    __shared__ float qs[C][8];       // qs[c][i]
    __shared__ float redm[8][4];
    __shared__ float reds[8][4];

    for (int e = t; e < C * 8; e += 256) {
        int c = e >> 3, i = e & 7;
        qs[c][i] = qp[((size_t)b * C + c) * L + l0 + i];
    }
    __syncthreads();

    const float2* __restrict__ kp2 =
        (const float2*)(kp + (size_t)b * C * L);

    float S[8][16];
    #pragma unroll
    for (int i = 0; i < 8; ++i)
        #pragma unroll
        for (int j = 0; j < 16; ++j) S[i][j] = 0.f;

    #pragma unroll 2
    for (int c = 0; c < C; ++c) {
        float q8[8];
        #pragma unroll
        for (int i = 0; i < 8; ++i) q8[i] = qs[c][i];
        float2 kr[8];
        #pragma unroll
        for (int j = 0; j < 8; ++j)
            kr[j] = kp2[(size_t)c * (L / 2) + t + 256 * j];
        #pragma unroll
        for (int i = 0; i < 8; ++i) {
            #pragma unroll
            for (int j = 0; j < 8; ++j) {
                S[i][2 * j]     = fmaf(q8[i], kr[j].x, S[i][2 * j]);
                S[i][2 * j + 1] = fmaf(q8[i], kr[j].y, S[i][2 * j + 1]);
            }
        }
    }

    // scale (applied before max, matching reference order)
    #pragma unroll
    for (int i = 0; i < 8; ++i)
        #pragma unroll
        for (int j = 0; j < 16; ++j) S[i][j] *= SCALE;

    int wave = t >> 6, lane = t & 63;

    // row max: per-thread -> wave shuffle -> cross-wave via LDS
    float rmax[8];
    #pragma unroll
    for (int i = 0; i < 8; ++i) {
        float m = S[i][0];
        #pragma unroll
        for (int j = 1; j < 16; ++j) m = fmaxf(m, S[i][j]);
        #pragma unroll
        for (int off = 1; off < 64; off <<= 1)
            m = fmaxf(m, __shfl_xor(m, off));
        rmax[i] = m;
    }
    if (lane == 0) {
        #pragma unroll
        for (int i = 0; i < 8; ++i) redm[i][wave] = rmax[i];
    }
    __syncthreads();
    float rowmax[8];
    #pragma unroll
    for (int i = 0; i < 8; ++i)
        rowmax[i] = fmaxf(fmaxf(redm[i][0], redm[i][1]),
                          fmaxf(redm[i][2], redm[i][3]));

    // exp + row sum
    #pragma unroll
    for (int i = 0; i < 8; ++i) {
        float s = 0.f;
        #pragma unroll
        for (int j = 0; j < 16; ++j) {
            float e = __expf(S[i][j] - rowmax[i]);
            S[i][j] = e;
            s += e;
        }
        #pragma unroll
        for (int off = 1; off < 64; off <<= 1)
            s += __shfl_xor(s, off);
        if (lane == 0) reds[i][wave] = s;
    }
    __syncthreads();

    float2* __restrict__ out2 = (float2*)out;
    #pragma unroll
    for (int i = 0; i < 8; ++i) {
        float inv = 1.0f / (reds[i][0] + reds[i][1] + reds[i][2] + reds[i][3]);
        size_t rowbase = ((size_t)b * L + l0 + i) * (size_t)(L / 2);
        #pragma unroll
        for (int j = 0; j < 8; ++j) {
            float wx = S[i][2 * j] * inv;
            float wy = S[i][2 * j + 1] * inv;
            float2 w2;
            w2.x = (wx > THRESH) ? wx : 0.0f;
            w2.y = (wy > THRESH) ? wy : 0.0f;
            out2[rowbase + t + 256 * j] = w2;
        }
    }
}

// ---------------------------------------------------------------------------
extern "C" void kernel_launch(void* const* d_in, const int* in_sizes, int n_in,
                              void* d_out, int out_size, void* d_ws, size_t ws_size,
                              hipStream_t stream) {
    const float* query = (const float*)d_in[0];
    const float* key   = (const float*)d_in[1];
    const float* W1    = (const float*)d_in[2];
    const float* W2    = (const float*)d_in[3];
    float* out = (float*)d_out;

    // workspace layout (floats): W2t[8192] | qp[4*64*4096] | kp[4*64*4096]
    float* W2t = (float*)d_ws;
    float* qp  = W2t + 8192;
    float* kp  = qp + (size_t)B * OUTC * L;

    hipLaunchKernelGGL(w2_transpose_kernel, dim3(32), dim3(256), 0, stream,
                       W2, W2t);
    hipLaunchKernelGGL(proj_kernel, dim3(512), dim3(64), 0, stream,
                       query, key, W1, W2t, qp, kp);
    hipLaunchKernelGGL(scores_kernel, dim3(2048), dim3(256), 0, stream,
                       qp, kp, out);
}

// Round 3
// 447.037 us; speedup vs baseline: 1.2115x; 1.2115x over previous
//
#include <hip/hip_runtime.h>
#include <math.h>

#define B 4
#define C 64
#define L 4096
#define OUTC 64
#define SCALE 10.0f
#define THRESH 1e-3f

typedef float v2f __attribute__((ext_vector_type(2)));
typedef float v4f __attribute__((ext_vector_type(4)));

__device__ __forceinline__ v2f pk_fma(v2f a, v2f b, v2f c) {
#if __has_builtin(__builtin_elementwise_fma)
    return __builtin_elementwise_fma(a, b, c);
#else
    v2f r; r.x = fmaf(a.x, b.x, c.x); r.y = fmaf(a.y, b.y, c.y); return r;
#endif
}

// ---------------------------------------------------------------------------
// Projection: p = l2norm(W2 @ leaky(W1 @ x)) per column.
// 512 blocks (2 inputs x 4 batches x 64 column-tiles) x 256 threads.
// Thread (g = t>>6, l = t&63): loads X column l into regs (coalesced global,
// L2-resident), computes H rows [g*32, g*32+32) -> LDS (b128 packed),
// then Y rows [g*16, g*16+16) from LDS H, l2norm across groups via LDS.
// W1/W2 indices are wave-uniform -> scalar-load path.
// ---------------------------------------------------------------------------
__global__ void __launch_bounds__(256) proj_kernel(
    const float* __restrict__ q_in, const float* __restrict__ k_in,
    const float* __restrict__ W1, const float* __restrict__ W2,
    float* __restrict__ qp, float* __restrict__ kp)
{
    int bid   = blockIdx.x;        // 0..511
    int which = bid >> 8;          // 0 = query, 1 = key
    int b     = (bid >> 6) & 3;
    int l0    = (bid & 63) << 6;
    int t     = threadIdx.x;
    int g     = t >> 6;            // 0..3
    int l     = t & 63;

    const float* __restrict__ src =
        (which ? k_in : q_in) + (size_t)b * C * L + l0 + l;
    float* __restrict__ dst =
        (which ? kp : qp) + (size_t)b * OUTC * L + l0 + l;

    __shared__ float Ht[64][132];   // [l][h], padded to 132 (16B-aligned rows)
    __shared__ float red[4][64];

    // X column into registers (64 coalesced global loads)
    float xr[C];
    #pragma unroll
    for (int c = 0; c < C; ++c)
        xr[c] = src[(size_t)c * L];

    // Stage 1: H[o][l] for o in [g*32, g*32+32), 4 at a time -> b128 LDS write
    #pragma unroll 1
    for (int oo = 0; oo < 32; oo += 4) {
        float h4[4];
        #pragma unroll
        for (int u = 0; u < 4; ++u) {
            int o = g * 32 + oo + u;
            float h0 = 0.f, h1 = 0.f, h2 = 0.f, h3 = 0.f;
            #pragma unroll
            for (int c = 0; c < C; c += 4) {
                h0 = fmaf(W1[o * C + c + 0], xr[c + 0], h0);
                h1 = fmaf(W1[o * C + c + 1], xr[c + 1], h1);
                h2 = fmaf(W1[o * C + c + 2], xr[c + 2], h2);
                h3 = fmaf(W1[o * C + c + 3], xr[c + 3], h3);
            }
            float h = (h0 + h1) + (h2 + h3);
            h4[u] = (h >= 0.0f) ? h : 0.01f * h;   // LeakyReLU(0.01)
        }
        *(v4f*)&Ht[l][g * 32 + oo] = (v4f){h4[0], h4[1], h4[2], h4[3]};
    }
    __syncthreads();

    // Stage 2: Y[o][l] for o in [g*16, g*16+16)
    float y[16];
    #pragma unroll
    for (int u = 0; u < 16; ++u) y[u] = 0.f;

    #pragma unroll 1
    for (int hh = 0; hh < 2 * C; hh += 16) {
        float hr[16];
        #pragma unroll
        for (int r = 0; r < 16; r += 4)
            *(v4f*)&hr[r] = *(const v4f*)&Ht[l][hh + r];
        #pragma unroll
        for (int u = 0; u < 16; ++u) {
            int o = g * 16 + u;
            #pragma unroll
            for (int h = 0; h < 16; ++h)
                y[u] = fmaf(W2[o * (2 * C) + hh + h], hr[h], y[u]);
        }
    }

    // l2norm over all 64 output channels (cross-group via LDS)
    float ss = 0.f;
    #pragma unroll
    for (int u = 0; u < 16; ++u) ss = fmaf(y[u], y[u], ss);
    red[g][l] = ss;
    __syncthreads();
    float tot = red[0][l] + red[1][l] + red[2][l] + red[3][l];
    float inv = 1.0f / fmaxf(sqrtf(tot), 1e-12f);

    #pragma unroll
    for (int u = 0; u < 16; ++u)
        dst[(size_t)(g * 16 + u) * L] = y[u] * inv;
}

// ---------------------------------------------------------------------------
// Scores + softmax + threshold. One block per (b, 16-row tile): 1024 blocks
// x 512 threads. Thread covers 16 rows x 8 cols (two float4 quads at t and
// t+512). q values are wave-uniform -> scalar loads; K streamed as float4;
// accumulators are packed v2f -> v_pk_fma_f32. No barriers in the main loop.
// ---------------------------------------------------------------------------
__global__ void __launch_bounds__(512) scores_kernel(
    const float* __restrict__ qp, const float* __restrict__ kp,
    float* __restrict__ out)
{
    int bid = blockIdx.x;            // 0..1023
    int b   = bid >> 8;              // /256
    int l0  = (bid & 255) << 4;      // *16 rows
    int t   = threadIdx.x;           // 0..511

    const v4f* __restrict__ kp4 = (const v4f*)(kp + (size_t)b * C * L);
    const float* __restrict__ qb = qp + (size_t)b * C * L;

    v2f S[16][4];
    #pragma unroll
    for (int i = 0; i < 16; ++i)
        #pragma unroll
        for (int j = 0; j < 4; ++j) S[i][j] = (v2f){0.f, 0.f};

    #pragma unroll 2
    for (int c = 0; c < C; ++c) {
        v4f k0 = kp4[c * (L / 4) + t];
        v4f k1 = kp4[c * (L / 4) + t + 512];
        v2f k00 = {k0.x, k0.y}, k01 = {k0.z, k0.w};
        v2f k10 = {k1.x, k1.y}, k11 = {k1.z, k1.w};
        const float* __restrict__ qrow = qb + (size_t)c * L + l0;
        #pragma unroll
        for (int i = 0; i < 16; ++i) {
            float qi = qrow[i];           // wave-uniform -> SGPR
            v2f qq = {qi, qi};
            S[i][0] = pk_fma(qq, k00, S[i][0]);
            S[i][1] = pk_fma(qq, k01, S[i][1]);
            S[i][2] = pk_fma(qq, k10, S[i][2]);
            S[i][3] = pk_fma(qq, k11, S[i][3]);
        }
    }

    int wave = t >> 6, lane = t & 63;
    __shared__ float redm[16][8];
    __shared__ float reds[16][8];

    // scale, then row max (wave shuffle -> cross-wave LDS)
    #pragma unroll
    for (int i = 0; i < 16; ++i) {
        #pragma unroll
        for (int j = 0; j < 4; ++j) S[i][j] *= (v2f){SCALE, SCALE};
        float m = fmaxf(fmaxf(fmaxf(S[i][0].x, S[i][0].y),
                              fmaxf(S[i][1].x, S[i][1].y)),
                        fmaxf(fmaxf(S[i][2].x, S[i][2].y),
                              fmaxf(S[i][3].x, S[i][3].y)));
        #pragma unroll
        for (int off = 1; off < 64; off <<= 1)
            m = fmaxf(m, __shfl_xor(m, off));
        if (lane == 0) redm[i][wave] = m;
    }
    __syncthreads();

    float rowm[16];
    #pragma unroll
    for (int i = 0; i < 16; ++i) {
        float m = redm[i][0];
        #pragma unroll
        for (int w = 1; w < 8; ++w) m = fmaxf(m, redm[i][w]);
        rowm[i] = m;
    }

    // exp + row sum
    #pragma unroll
    for (int i = 0; i < 16; ++i) {
        float s = 0.f;
        #pragma unroll
        for (int j = 0; j < 4; ++j) {
            float ex = __expf(S[i][j].x - rowm[i]);
            float ey = __expf(S[i][j].y - rowm[i]);
            S[i][j] = (v2f){ex, ey};
            s += ex + ey;
        }
        #pragma unroll
        for (int off = 1; off < 64; off <<= 1)
            s += __shfl_xor(s, off);
        if (lane == 0) reds[i][wave] = s;
    }
    __syncthreads();

    v4f* __restrict__ out4 = (v4f*)out;
    #pragma unroll
    for (int i = 0; i < 16; ++i) {
        float tot = 0.f;
        #pragma unroll
        for (int w = 0; w < 8; ++w) tot += reds[i][w];
        float inv = 1.0f / tot;
        size_t rowbase = ((size_t)b * L + l0 + i) * (size_t)(L / 4);
        float w0 = S[i][0].x * inv, w1 = S[i][0].y * inv;
        float w2 = S[i][1].x * inv, w3 = S[i][1].y * inv;
        float w4 = S[i][2].x * inv, w5 = S[i][2].y * inv;
        float w6 = S[i][3].x * inv, w7 = S[i][3].y * inv;
        v4f r0 = {(w0 > THRESH) ? w0 : 0.f, (w1 > THRESH) ? w1 : 0.f,
                  (w2 > THRESH) ? w2 : 0.f, (w3 > THRESH) ? w3 : 0.f};
        v4f r1 = {(w4 > THRESH) ? w4 : 0.f, (w5 > THRESH) ? w5 : 0.f,
                  (w6 > THRESH) ? w6 : 0.f, (w7 > THRESH) ? w7 : 0.f};
        out4[rowbase + t]       = r0;
        out4[rowbase + t + 512] = r1;
    }
}

// ---------------------------------------------------------------------------
extern "C" void kernel_launch(void* const* d_in, const int* in_sizes, int n_in,
                              void* d_out, int out_size, void* d_ws, size_t ws_size,
                              hipStream_t stream) {
    const float* query = (const float*)d_in[0];
    const float* key   = (const float*)d_in[1];
    const float* W1    = (const float*)d_in[2];
    const float* W2    = (const float*)d_in[3];
    float* out = (float*)d_out;

    // workspace layout (floats): qp[4*64*4096] | kp[4*64*4096]
    float* qp = (float*)d_ws;
    float* kp = qp + (size_t)B * OUTC * L;

    hipLaunchKernelGGL(proj_kernel, dim3(512), dim3(256), 0, stream,
                       query, key, W1, W2, qp, kp);
    hipLaunchKernelGGL(scores_kernel, dim3(1024), dim3(512), 0, stream,
                       qp, kp, out);
}